// Round 2
// baseline (925.026 us; speedup 1.0000x reference)
//
#include <hip/hip_runtime.h>
#include <hip/hip_bf16.h>
#include <stdint.h>

// Problem constants (from reference)
#define IN_F 4096
#define OUT_F 11008
#define M_ROWS 8192              // 4 * 2048
#define NIG 512                  // IN_FEATURES / IN_GROUP(8)
#define CBSZ 256

typedef _Float16 f16x8 __attribute__((ext_vector_type(8)));
typedef float f32x4 __attribute__((ext_vector_type(4)));

// ---------------------------------------------------------------------------
// Kernel 1: dequantize W (UNSCALED: scales applied in GEMM epilogue in fp32).
// ---------------------------------------------------------------------------
__global__ __launch_bounds__(256) void dequant_w_kernel(
    const int* __restrict__ codes, const float* __restrict__ cbs,
    _Float16* __restrict__ W)
{
  const int idx = blockIdx.x * 256 + threadIdx.x;   // o*512 + g (exact grid)
  const int2 c = ((const int2*)codes)[idx];
  const float4* e0 = (const float4*)(cbs + (size_t)c.x * 8);
  const float4* e1 = (const float4*)(cbs + (size_t)CBSZ * 8 + (size_t)c.y * 8);
  const float4 a0 = e0[0], a1 = e0[1];
  const float4 b0 = e1[0], b1 = e1[1];
  f16x8 w;
  w[0] = (_Float16)(a0.x + b0.x);
  w[1] = (_Float16)(a0.y + b0.y);
  w[2] = (_Float16)(a0.z + b0.z);
  w[3] = (_Float16)(a0.w + b0.w);
  w[4] = (_Float16)(a1.x + b1.x);
  w[5] = (_Float16)(a1.y + b1.y);
  w[6] = (_Float16)(a1.z + b1.z);
  w[7] = (_Float16)(a1.w + b1.w);
  *(f16x8*)(W + (size_t)idx * 8) = w;
}

// ---------------------------------------------------------------------------
// Kernel 2: x fp32 -> f16, 8 elems/thread, vectorized.
// ---------------------------------------------------------------------------
__global__ __launch_bounds__(256) void convert_x_kernel(
    const float* __restrict__ x, _Float16* __restrict__ X)
{
  const size_t i = ((size_t)blockIdx.x * 256 + threadIdx.x) * 8;
  const float4 a = *(const float4*)(x + i);
  const float4 b = *(const float4*)(x + i + 4);
  f16x8 v;
  v[0] = (_Float16)a.x; v[1] = (_Float16)a.y;
  v[2] = (_Float16)a.z; v[3] = (_Float16)a.w;
  v[4] = (_Float16)b.x; v[5] = (_Float16)b.y;
  v[6] = (_Float16)b.z; v[7] = (_Float16)b.w;
  *(f16x8*)(X + i) = v;
}

// ---------------------------------------------------------------------------
// Kernel 3: 256x256x64 f16 MFMA GEMM, phase-split schedule (T2+T3+T5).
// 512 threads = 8 waves (2M x 4N); per-wave output 128x64 (8x4 16x16 frags).
// LDS: 2 x (A 32KB + B 32KB) double-buffer = 128 KB.
// LDS layout: [16x32]-f16 subtiles (1024B), swizzle colb ^= ((row&8)<<2)^((row&4)<<2)
//   -> 2 lanes/bank on ds_read_b128 (conflict-free). global_load_lds writes
//   LINEAR; source address is pre-swizzled (rule #21, involution both sides).
// Schedule per K-tile j (4 phases): P1 issues ALL 8 stage-loads for j+1 into
// the other buffer (safe: j-1's reads completed at previous __syncthreads),
// then reads A-lo+B-lo, MFMA Q1; P2: read B-hi, Q2; P3: read A-hi, Q3;
// P4: Q4, then ONE __syncthreads (vmcnt drain ~3 phases after issue).
// Raw s_barrier pairs around each MFMA cluster shape the interleave (m196);
// correctness rests only on __syncthreads (full fence).
// ---------------------------------------------------------------------------
#define BM 256
#define BN 256
#define BK 64
#define NKT (IN_F / BK)          // 64
#define GRID_MT (M_ROWS / BM)    // 32
#define GRID_NT (OUT_F / BN)     // 43

__global__ __launch_bounds__(512, 2) void gemm_8phase(
    const _Float16* __restrict__ X, const _Float16* __restrict__ Wd,
    const float* __restrict__ scales, const float* __restrict__ bias,
    float* __restrict__ out)
{
  __shared__ char smem[131072];  // [2 bufs][A 32KB | B 32KB]

  // T1: XCD-aware swizzle; nwg = 1376, 1376 % 8 == 0 -> simple form bijective
  const int cpx = (GRID_MT * GRID_NT) >> 3;        // 172
  const int wg = (blockIdx.x & 7) * cpx + (blockIdx.x >> 3);
  const int mt = wg & 31, nt = wg >> 5;            // m-inner: blocks sharing B-panel land on same XCD
  const int m0 = mt * BM, n0 = nt * BN;

  const int t = threadIdx.x;
  const int wave = t >> 6, lane = t & 63;
  const int wm = wave >> 2, wn = wave & 3;
  const int r16 = lane & 15;
  const int koff2 = (lane >> 4) << 4;              // k-chunk byte offset {0,16,32,48}
  const int Xr = ((r16 & 8) << 2) | ((r16 & 4) << 2);
  const int laneoff = r16 * 64 + (koff2 ^ Xr);     // swizzled read offset within subtile pair

  // Staging source pre-swizzle (hand-verified round-trip):
  // thread t, issue i writes LDS linear (i*512+t)*16; the element that must
  // live there is row = i*64 + (t>>7)*16 + ((t>>2)&15),
  //              col = ((t>>6)&1)*32 + ((((t&3)<<4) ^ (t&48)) >> 1)
  const int s_row0 = ((t >> 7) << 4) | ((t >> 2) & 15);
  const int s_col  = (((t >> 6) & 1) << 5) | (((((t & 3) << 4) ^ (t & 48))) >> 1);
  const _Float16* asrc = X  + (size_t)(m0 + s_row0) * IN_F + s_col;
  const _Float16* bsrc = Wd + (size_t)(n0 + s_row0) * IN_F + s_col;
  const int s_dst = wave * 1024;                   // wave-uniform; HW adds lane*16

  f32x4 acc[8][4] = {};
  f16x8 alo[4][2], ahi[4][2], blo[2][2], bhi[2][2];

#define STAGE(kt, b) do {                                                     \
    const _Float16* _a = asrc + (size_t)(kt) * BK;                            \
    const _Float16* _b = bsrc + (size_t)(kt) * BK;                            \
    _Pragma("unroll")                                                         \
    for (int i = 0; i < 4; ++i)                                               \
      __builtin_amdgcn_global_load_lds(                                       \
        (const __attribute__((address_space(1))) void*)(_a + (size_t)i * 64 * IN_F), \
        (__attribute__((address_space(3))) void*)(smem + (b) * 65536 + i * 8192 + s_dst), \
        16, 0, 0);                                                            \
    _Pragma("unroll")                                                         \
    for (int i = 0; i < 4; ++i)                                               \
      __builtin_amdgcn_global_load_lds(                                       \
        (const __attribute__((address_space(1))) void*)(_b + (size_t)i * 64 * IN_F), \
        (__attribute__((address_space(3))) void*)(smem + (b) * 65536 + 32768 + i * 8192 + s_dst), \
        16, 0, 0);                                                            \
  } while (0)

  STAGE(0, 0);
  __syncthreads();                                 // vmcnt(0): tile 0 landed

  for (int j = 0; j < NKT; ++j) {
    const int cur = j & 1;
    const char* Ab = smem + cur * 65536;
    const char* Bb = smem + cur * 65536 + 32768;

    // ---- P1: issue next-tile stage; read A-lo + B-lo (12 b128); MFMA Q1 ----
    if (j + 1 < NKT) STAGE(j + 1, cur ^ 1);
    #pragma unroll
    for (int m = 0; m < 4; ++m)
      #pragma unroll
      for (int k = 0; k < 2; ++k)
        alo[m][k] = *(const f16x8*)(Ab + (wm * 8 + m) * 2048 + k * 1024 + laneoff);
    #pragma unroll
    for (int n = 0; n < 2; ++n)
      #pragma unroll
      for (int k = 0; k < 2; ++k)
        blo[n][k] = *(const f16x8*)(Bb + (wn * 4 + n) * 2048 + k * 1024 + laneoff);
    __builtin_amdgcn_s_barrier();
    __builtin_amdgcn_s_setprio(1);
    #pragma unroll
    for (int k = 0; k < 2; ++k)
      #pragma unroll
      for (int m = 0; m < 4; ++m)
        #pragma unroll
        for (int n = 0; n < 2; ++n)
          acc[m][n] = __builtin_amdgcn_mfma_f32_16x16x32_f16(alo[m][k], blo[n][k], acc[m][n], 0, 0, 0);
    __builtin_amdgcn_s_setprio(0);
    __builtin_amdgcn_s_barrier();

    // ---- P2: read B-hi (4 b128); MFMA Q2 = A-lo x B-hi ----
    #pragma unroll
    for (int n = 0; n < 2; ++n)
      #pragma unroll
      for (int k = 0; k < 2; ++k)
        bhi[n][k] = *(const f16x8*)(Bb + (wn * 4 + 2 + n) * 2048 + k * 1024 + laneoff);
    __builtin_amdgcn_s_barrier();
    __builtin_amdgcn_s_setprio(1);
    #pragma unroll
    for (int k = 0; k < 2; ++k)
      #pragma unroll
      for (int m = 0; m < 4; ++m)
        #pragma unroll
        for (int n = 0; n < 2; ++n)
          acc[m][2 + n] = __builtin_amdgcn_mfma_f32_16x16x32_f16(alo[m][k], bhi[n][k], acc[m][2 + n], 0, 0, 0);
    __builtin_amdgcn_s_setprio(0);
    __builtin_amdgcn_s_barrier();

    // ---- P3: read A-hi (8 b128); MFMA Q3 = A-hi x B-hi ----
    #pragma unroll
    for (int m = 0; m < 4; ++m)
      #pragma unroll
      for (int k = 0; k < 2; ++k)
        ahi[m][k] = *(const f16x8*)(Ab + (wm * 8 + 4 + m) * 2048 + k * 1024 + laneoff);
    __builtin_amdgcn_s_barrier();
    __builtin_amdgcn_s_setprio(1);
    #pragma unroll
    for (int k = 0; k < 2; ++k)
      #pragma unroll
      for (int m = 0; m < 4; ++m)
        #pragma unroll
        for (int n = 0; n < 2; ++n)
          acc[4 + m][2 + n] = __builtin_amdgcn_mfma_f32_16x16x32_f16(ahi[m][k], bhi[n][k], acc[4 + m][2 + n], 0, 0, 0);
    __builtin_amdgcn_s_setprio(0);
    __builtin_amdgcn_s_barrier();

    // ---- P4: MFMA Q4 = A-hi x B-lo; single drain point of the K-step ----
    __builtin_amdgcn_s_setprio(1);
    #pragma unroll
    for (int k = 0; k < 2; ++k)
      #pragma unroll
      for (int m = 0; m < 4; ++m)
        #pragma unroll
        for (int n = 0; n < 2; ++n)
          acc[4 + m][n] = __builtin_amdgcn_mfma_f32_16x16x32_f16(ahi[m][k], blo[n][k], acc[4 + m][n], 0, 0, 0);
    __builtin_amdgcn_s_setprio(0);
    __syncthreads();   // vmcnt(0)+lgkmcnt(0)+barrier: next tile landed; all
                       // reads of buf[cur] done -> next P1 may stage into it
  }

  // Epilogue: acc * scales[col] + bias[col], fp32.
  // C/D frag: col = lane&15, row = (lane>>4)*4 + reg (m89-verified).
  const int crow = (lane >> 4) << 2;
  #pragma unroll
  for (int nf = 0; nf < 4; ++nf) {
    const int col = n0 + wn * 64 + nf * 16 + r16;
    const float s = scales[col];
    const float bb = bias[col];
    #pragma unroll
    for (int mf = 0; mf < 8; ++mf) {
      const int rb = m0 + wm * 128 + mf * 16 + crow;
      #pragma unroll
      for (int r = 0; r < 4; ++r)
        out[(size_t)(rb + r) * OUT_F + col] = acc[mf][nf][r] * s + bb;
    }
  }
#undef STAGE
}

// ---------------------------------------------------------------------------
// Fallback (only if ws too small): correct but slow fp32 path.
// ---------------------------------------------------------------------------
__global__ __launch_bounds__(256) void naive_kernel(
    const float* __restrict__ x, const int* __restrict__ codes,
    const float* __restrict__ cbs, const float* __restrict__ scales,
    const float* __restrict__ bias, float* __restrict__ out)
{
  __shared__ float xrow[IN_F];
  const int m = blockIdx.x;
  for (int i = threadIdx.x; i < IN_F; i += 256)
    xrow[i] = x[(size_t)m * IN_F + i];
  __syncthreads();
  for (int o = threadIdx.x; o < OUT_F; o += 256) {
    float acc = 0.f;
    const int2* crow = (const int2*)codes + (size_t)o * NIG;
    for (int g = 0; g < NIG; ++g) {
      const int2 c = crow[g];
      const float* e0 = cbs + (size_t)c.x * 8;
      const float* e1 = cbs + (size_t)CBSZ * 8 + (size_t)c.y * 8;
      const float* xr = xrow + g * 8;
      #pragma unroll
      for (int j = 0; j < 8; ++j) acc += (e0[j] + e1[j]) * xr[j];
    }
    out[(size_t)m * OUT_F + o] = acc * scales[o] + bias[o];
  }
}

// ---------------------------------------------------------------------------
extern "C" void kernel_launch(void* const* d_in, const int* in_sizes, int n_in,
                              void* d_out, int out_size, void* d_ws, size_t ws_size,
                              hipStream_t stream) {
  const float* x      = (const float*)d_in[0];
  const int*   codes  = (const int*)d_in[1];
  const float* cbs    = (const float*)d_in[2];
  const float* scales = (const float*)d_in[3];
  const float* bias   = (const float*)d_in[4];
  float* out = (float*)d_out;

  const size_t W_BYTES = (size_t)OUT_F * IN_F * sizeof(_Float16); // 90.2 MB
  const size_t X_BYTES = (size_t)M_ROWS * IN_F * sizeof(_Float16); // 67.1 MB

  if (ws_size < W_BYTES + X_BYTES) {
    naive_kernel<<<M_ROWS, 256, 0, stream>>>(x, codes, cbs, scales, bias, out);
    return;
  }

  _Float16* W = (_Float16*)d_ws;
  _Float16* X = (_Float16*)((char*)d_ws + W_BYTES);

  dequant_w_kernel<<<(OUT_F * NIG) / 256, 256, 0, stream>>>(codes, cbs, W);
  convert_x_kernel<<<(M_ROWS * IN_F / 8) / 256, 256, 0, stream>>>(x, X);
  gemm_8phase<<<GRID_MT * GRID_NT, 512, 0, stream>>>(X, W, scales, bias, out);
}

// Round 3
// 910.765 us; speedup vs baseline: 1.0157x; 1.0157x over previous
//
#include <hip/hip_runtime.h>
#include <hip/hip_bf16.h>
#include <stdint.h>

// Problem constants (from reference)
#define IN_F 4096
#define OUT_F 11008
#define M_ROWS 8192              // 4 * 2048
#define NIG 512                  // IN_FEATURES / IN_GROUP(8)
#define CBSZ 256

typedef _Float16 f16x8 __attribute__((ext_vector_type(8)));
typedef float f32x4 __attribute__((ext_vector_type(4)));

// ---------------------------------------------------------------------------
// Kernel 1: dequantize W (UNSCALED: scales applied in GEMM epilogue in fp32).
// ---------------------------------------------------------------------------
__global__ __launch_bounds__(256) void dequant_w_kernel(
    const int* __restrict__ codes, const float* __restrict__ cbs,
    _Float16* __restrict__ W)
{
  const int idx = blockIdx.x * 256 + threadIdx.x;   // o*512 + g (exact grid)
  const int2 c = ((const int2*)codes)[idx];
  const float4* e0 = (const float4*)(cbs + (size_t)c.x * 8);
  const float4* e1 = (const float4*)(cbs + (size_t)CBSZ * 8 + (size_t)c.y * 8);
  const float4 a0 = e0[0], a1 = e0[1];
  const float4 b0 = e1[0], b1 = e1[1];
  f16x8 w;
  w[0] = (_Float16)(a0.x + b0.x);
  w[1] = (_Float16)(a0.y + b0.y);
  w[2] = (_Float16)(a0.z + b0.z);
  w[3] = (_Float16)(a0.w + b0.w);
  w[4] = (_Float16)(a1.x + b1.x);
  w[5] = (_Float16)(a1.y + b1.y);
  w[6] = (_Float16)(a1.z + b1.z);
  w[7] = (_Float16)(a1.w + b1.w);
  *(f16x8*)(W + (size_t)idx * 8) = w;
}

// ---------------------------------------------------------------------------
// Kernel 2: x fp32 -> f16, 8 elems/thread, vectorized.
// ---------------------------------------------------------------------------
__global__ __launch_bounds__(256) void convert_x_kernel(
    const float* __restrict__ x, _Float16* __restrict__ X)
{
  const size_t i = ((size_t)blockIdx.x * 256 + threadIdx.x) * 8;
  const float4 a = *(const float4*)(x + i);
  const float4 b = *(const float4*)(x + i + 4);
  f16x8 v;
  v[0] = (_Float16)a.x; v[1] = (_Float16)a.y;
  v[2] = (_Float16)a.z; v[3] = (_Float16)a.w;
  v[4] = (_Float16)b.x; v[5] = (_Float16)b.y;
  v[6] = (_Float16)b.z; v[7] = (_Float16)b.w;
  *(f16x8*)(X + i) = v;
}

// ---------------------------------------------------------------------------
// Kernel 3: 256x256x64 f16 GEMM, m201-style pipeline with COUNTED vmcnt (T4).
// 512 threads = 8 waves (2M x 4N); per-wave output 128x64 (8x4 16x16 frags).
// LDS: 2 x (A [256][64] f16 32KB | B [256][64] f16 32KB) = 128 KB.
// Swizzle (m201 st_16x32, measured-zero conflicts): byte ^= ((row&4)<<3),
// applied on the READ address and inverted on the STAGING GLOBAL SOURCE
// (LDS dest stays linear per global_load_lds rules).
// Schedule per K-tile j (buf cur=j&1):
//   P1 { ds_read A-lo(8)+B-lo(4); BAR; prio1 16xMFMA Q1 prio0; BAR }
//   P2 { ds_read B-hi(4);         BAR; Q2; BAR }
//   P3 { ds_read A-hi(8);         BAR; Q3; BAR }
//   P4 { STAGE(j+2 -> buf[cur]);  BAR; Q4; s_waitcnt vmcnt(8); BAR }
// WAR safety of STAGE(j+2, buf[cur]): every wave passed P3-end BAR, which is
// after all waves consumed their buf[cur] reads (lgkm before Q1-Q3 MFMAs).
// RAW: vmcnt(8) at P4 leaves exactly the 8 just-issued loads in flight and
// guarantees tile j+1's 8 loads (issued at tile j-1 P4) have landed; the
// following BAR publishes. vmcnt never hits 0 until tile 62 (edge).
// ---------------------------------------------------------------------------
#define BM 256
#define BN 256
#define BK 64
#define NKT (IN_F / BK)          // 64
#define GRID_MT (M_ROWS / BM)    // 32
#define GRID_NT (OUT_F / BN)     // 43

__global__ __launch_bounds__(512, 2) void gemm_pipe(
    const _Float16* __restrict__ X, const _Float16* __restrict__ Wd,
    const float* __restrict__ scales, const float* __restrict__ bias,
    float* __restrict__ out)
{
  __shared__ char smem[131072];  // [2 bufs][A 32KB | B 32KB]

  // T1: XCD swizzle; nwg = 1376 % 8 == 0 -> simple form bijective
  const int cpx = (GRID_MT * GRID_NT) >> 3;        // 172
  const int wg = (blockIdx.x & 7) * cpx + (blockIdx.x >> 3);
  const int mt = wg & (GRID_MT - 1), nt = wg >> 5; // m-inner: same B-panel per XCD
  const int m0 = mt * BM, n0 = nt * BN;

  const int t = threadIdx.x;
  const int wave = t >> 6, lane = t & 63;
  const int wm = wave >> 2, wn = wave & 3;
  const int r16 = lane & 15;
  // swizzled 16B-chunk offset within a 64B k-half: chunk ^ ((row&4)<<3), row&4 == r16&4
  const int ko = (((lane >> 4) << 4) ^ ((r16 & 4) << 3));

  // Staging: thread t's 16B lands at linear LDS byte (issue*8192 + t*16)
  //   -> row = issue*64 + (t>>3), colb = (t&7)*16.
  // Content there must be element chunk colb ^ ((row&4)<<3); row&4 = (t>>5)&1 ? 4 : 0.
  // Global f16 col = ((t&7)*8) ^ ((t&32)>>1).  (round-trip verified)
  const int s_row0 = t >> 3;
  const int s_col  = ((t & 7) << 3) ^ ((t & 32) >> 1);
  const _Float16* asrc = X  + (size_t)(m0 + s_row0) * IN_F + s_col;
  const _Float16* bsrc = Wd + (size_t)(n0 + s_row0) * IN_F + s_col;
  const int s_dst = wave * 1024;                   // wave-uniform; HW adds lane*16

  f32x4 acc[8][4] = {};
  f16x8 alo[4][2], ahi[4][2], blo[2][2], bhi[2][2];

#define STAGE(kt, b) do {                                                     \
    const _Float16* _a = asrc + (size_t)(kt) * BK;                            \
    const _Float16* _b = bsrc + (size_t)(kt) * BK;                            \
    _Pragma("unroll")                                                         \
    for (int i = 0; i < 4; ++i)                                               \
      __builtin_amdgcn_global_load_lds(                                       \
        (const __attribute__((address_space(1))) void*)(_a + (size_t)i * 64 * IN_F), \
        (__attribute__((address_space(3))) void*)(smem + (b) * 65536 + i * 8192 + s_dst), \
        16, 0, 0);                                                            \
    _Pragma("unroll")                                                         \
    for (int i = 0; i < 4; ++i)                                               \
      __builtin_amdgcn_global_load_lds(                                       \
        (const __attribute__((address_space(1))) void*)(_b + (size_t)i * 64 * IN_F), \
        (__attribute__((address_space(3))) void*)(smem + (b) * 65536 + 32768 + i * 8192 + s_dst), \
        16, 0, 0);                                                            \
  } while (0)

#define BAR   __builtin_amdgcn_s_barrier()
#define PRIO1 __builtin_amdgcn_s_setprio(1)
#define PRIO0 __builtin_amdgcn_s_setprio(0)
#define VMCNT8 asm volatile("s_waitcnt vmcnt(8)" ::: "memory")
#define VMCNT0 asm volatile("s_waitcnt vmcnt(0)" ::: "memory")

// Q-cluster: 16 MFMAs accumulating one C quadrant over K=64
#define QUAD(AM, BM_, AOFF, BOFF)                                             \
    _Pragma("unroll")                                                         \
    for (int k = 0; k < 2; ++k)                                               \
      _Pragma("unroll")                                                       \
      for (int m = 0; m < 4; ++m)                                             \
        _Pragma("unroll")                                                     \
        for (int n = 0; n < 2; ++n)                                           \
          acc[(AOFF) + m][(BOFF) + n] =                                       \
            __builtin_amdgcn_mfma_f32_16x16x32_f16(AM[m][k], BM_[n][k],       \
                                                   acc[(AOFF) + m][(BOFF) + n], 0, 0, 0)

// One K-tile: STG = stage tile (jj+2) into buf[cur]; W8/W0 = wait flavor
#define TILE(cur, jj, STG, W8, W0) do {                                       \
    const char* Ab = smem + (cur) * 65536;                                    \
    const char* Bb = Ab + 32768;                                              \
    /* P1: A-lo + B-lo reads, Q1 */                                           \
    _Pragma("unroll")                                                         \
    for (int m = 0; m < 4; ++m)                                               \
      _Pragma("unroll")                                                       \
      for (int k = 0; k < 2; ++k)                                             \
        alo[m][k] = *(const f16x8*)(Ab + ((wm * 128 + m * 16 + r16) << 7) + (k << 6) + ko); \
    _Pragma("unroll")                                                         \
    for (int n = 0; n < 2; ++n)                                               \
      _Pragma("unroll")                                                       \
      for (int k = 0; k < 2; ++k)                                             \
        blo[n][k] = *(const f16x8*)(Bb + ((wn * 64 + n * 16 + r16) << 7) + (k << 6) + ko); \
    BAR; PRIO1; QUAD(alo, blo, 0, 0); PRIO0; BAR;                             \
    /* P2: B-hi reads, Q2 */                                                  \
    _Pragma("unroll")                                                         \
    for (int n = 0; n < 2; ++n)                                               \
      _Pragma("unroll")                                                       \
      for (int k = 0; k < 2; ++k)                                             \
        bhi[n][k] = *(const f16x8*)(Bb + ((wn * 64 + (2 + n) * 16 + r16) << 7) + (k << 6) + ko); \
    BAR; PRIO1; QUAD(alo, bhi, 0, 2); PRIO0; BAR;                             \
    /* P3: A-hi reads, Q3 */                                                  \
    _Pragma("unroll")                                                         \
    for (int m = 0; m < 4; ++m)                                               \
      _Pragma("unroll")                                                       \
      for (int k = 0; k < 2; ++k)                                             \
        ahi[m][k] = *(const f16x8*)(Ab + ((wm * 128 + (4 + m) * 16 + r16) << 7) + (k << 6) + ko); \
    BAR; PRIO1; QUAD(ahi, bhi, 4, 2); PRIO0; BAR;                             \
    /* P4: stage j+2 into buf[cur] (all buf[cur] reads consumed by P3-end BAR) */ \
    if (STG) STAGE((jj) + 2, cur);                                            \
    BAR; PRIO1; QUAD(ahi, blo, 4, 0); PRIO0;                                  \
    if (W8) { VMCNT8; }                                                       \
    if (W0) { VMCNT0; }                                                       \
    if ((W8) || (W0)) BAR;  /* publish tile jj+1 */                           \
  } while (0)

  // Prologue: stage tiles 0 and 1; publish tile 0 with tile 1 still in flight
  STAGE(0, 0);
  STAGE(1, 1);
  VMCNT8;
  BAR;

  // Tiles 0..61: full pipeline (stage jj+2, counted wait vmcnt(8))
  #pragma unroll 1
  for (int jj = 0; jj < 62; jj += 2) {
    TILE(0, jj, 1, 1, 0);
    TILE(1, jj + 1, 1, 1, 0);
  }
  // Tile 62: no stage left; drain (edge) and publish tile 63
  TILE(0, 62, 0, 0, 1);
  // Tile 63: last; no stage, no wait
  TILE(1, 63, 0, 0, 0);

  // Epilogue: acc * scales[col] + bias[col], fp32.
  // C/D frag: col = lane&15, row = (lane>>4)*4 + reg (m89-verified).
  const int crow = (lane >> 4) << 2;
  #pragma unroll
  for (int nf = 0; nf < 4; ++nf) {
    const int col = n0 + wn * 64 + nf * 16 + r16;
    const float s = scales[col];
    const float bb = bias[col];
    #pragma unroll
    for (int mf = 0; mf < 8; ++mf) {
      const int rb = m0 + wm * 128 + mf * 16 + crow;
      #pragma unroll
      for (int r = 0; r < 4; ++r)
        out[(size_t)(rb + r) * OUT_F + col] = acc[mf][nf][r] * s + bb;
    }
  }
#undef TILE
#undef QUAD
#undef STAGE
}

// ---------------------------------------------------------------------------
// Fallback (only if ws too small): correct but slow fp32 path.
// ---------------------------------------------------------------------------
__global__ __launch_bounds__(256) void naive_kernel(
    const float* __restrict__ x, const int* __restrict__ codes,
    const float* __restrict__ cbs, const float* __restrict__ scales,
    const float* __restrict__ bias, float* __restrict__ out)
{
  __shared__ float xrow[IN_F];
  const int m = blockIdx.x;
  for (int i = threadIdx.x; i < IN_F; i += 256)
    xrow[i] = x[(size_t)m * IN_F + i];
  __syncthreads();
  for (int o = threadIdx.x; o < OUT_F; o += 256) {
    float acc = 0.f;
    const int2* crow = (const int2*)codes + (size_t)o * NIG;
    for (int g = 0; g < NIG; ++g) {
      const int2 c = crow[g];
      const float* e0 = cbs + (size_t)c.x * 8;
      const float* e1 = cbs + (size_t)CBSZ * 8 + (size_t)c.y * 8;
      const float* xr = xrow + g * 8;
      #pragma unroll
      for (int j = 0; j < 8; ++j) acc += (e0[j] + e1[j]) * xr[j];
    }
    out[(size_t)m * OUT_F + o] = acc * scales[o] + bias[o];
  }
}

// ---------------------------------------------------------------------------
extern "C" void kernel_launch(void* const* d_in, const int* in_sizes, int n_in,
                              void* d_out, int out_size, void* d_ws, size_t ws_size,
                              hipStream_t stream) {
  const float* x      = (const float*)d_in[0];
  const int*   codes  = (const int*)d_in[1];
  const float* cbs    = (const float*)d_in[2];
  const float* scales = (const float*)d_in[3];
  const float* bias   = (const float*)d_in[4];
  float* out = (float*)d_out;

  const size_t W_BYTES = (size_t)OUT_F * IN_F * sizeof(_Float16);  // 90.2 MB
  const size_t X_BYTES = (size_t)M_ROWS * IN_F * sizeof(_Float16); // 67.1 MB

  if (ws_size < W_BYTES + X_BYTES) {
    naive_kernel<<<M_ROWS, 256, 0, stream>>>(x, codes, cbs, scales, bias, out);
    return;
  }

  _Float16* W = (_Float16*)d_ws;
  _Float16* X = (_Float16*)((char*)d_ws + W_BYTES);

  dequant_w_kernel<<<(OUT_F * NIG) / 256, 256, 0, stream>>>(codes, cbs, W);
  convert_x_kernel<<<(M_ROWS * IN_F / 8) / 256, 256, 0, stream>>>(x, X);
  gemm_pipe<<<GRID_MT * GRID_NT, 512, 0, stream>>>(X, W, scales, bias, out);
}

// Round 4
// 839.483 us; speedup vs baseline: 1.1019x; 1.0849x over previous
//
#include <hip/hip_runtime.h>
#include <hip/hip_bf16.h>
#include <stdint.h>

// Problem constants (from reference)
#define IN_F 4096
#define OUT_F 11008
#define M_ROWS 8192              // 4 * 2048
#define NIG 512                  // IN_FEATURES / IN_GROUP(8)
#define CBSZ 256

typedef _Float16 f16x8 __attribute__((ext_vector_type(8)));
typedef float f32x4 __attribute__((ext_vector_type(4)));

// ---------------------------------------------------------------------------
// Kernel 1: dequantize W (UNSCALED: scales applied in GEMM epilogue in fp32).
// ---------------------------------------------------------------------------
__global__ __launch_bounds__(256) void dequant_w_kernel(
    const int* __restrict__ codes, const float* __restrict__ cbs,
    _Float16* __restrict__ W)
{
  const int idx = blockIdx.x * 256 + threadIdx.x;   // o*512 + g (exact grid)
  const int2 c = ((const int2*)codes)[idx];
  const float4* e0 = (const float4*)(cbs + (size_t)c.x * 8);
  const float4* e1 = (const float4*)(cbs + (size_t)CBSZ * 8 + (size_t)c.y * 8);
  const float4 a0 = e0[0], a1 = e0[1];
  const float4 b0 = e1[0], b1 = e1[1];
  f16x8 w;
  w[0] = (_Float16)(a0.x + b0.x);
  w[1] = (_Float16)(a0.y + b0.y);
  w[2] = (_Float16)(a0.z + b0.z);
  w[3] = (_Float16)(a0.w + b0.w);
  w[4] = (_Float16)(a1.x + b1.x);
  w[5] = (_Float16)(a1.y + b1.y);
  w[6] = (_Float16)(a1.z + b1.z);
  w[7] = (_Float16)(a1.w + b1.w);
  *(f16x8*)(W + (size_t)idx * 8) = w;
}

// ---------------------------------------------------------------------------
// Kernel 2: x fp32 -> f16, 8 elems/thread, vectorized.
// ---------------------------------------------------------------------------
__global__ __launch_bounds__(256) void convert_x_kernel(
    const float* __restrict__ x, _Float16* __restrict__ X)
{
  const size_t i = ((size_t)blockIdx.x * 256 + threadIdx.x) * 8;
  const float4 a = *(const float4*)(x + i);
  const float4 b = *(const float4*)(x + i + 4);
  f16x8 v;
  v[0] = (_Float16)a.x; v[1] = (_Float16)a.y;
  v[2] = (_Float16)a.z; v[3] = (_Float16)a.w;
  v[4] = (_Float16)b.x; v[5] = (_Float16)b.y;
  v[6] = (_Float16)b.z; v[7] = (_Float16)b.w;
  *(f16x8*)(X + i) = v;
}

// ---------------------------------------------------------------------------
// Kernel 3: 256x256x64 f16 GEMM, counted-vmcnt pipeline (T3+T4), T5 setprio.
// 512 threads = 8 waves (2M x 4N); per-wave output 128x64 (8x4 16x16 frags).
// LDS: 2 x (A [256][64] f16 32KB | B [256][64] f16 32KB) = 128 KB.
//
// BANK-CONFLICT FIX (round 4): row stride is 128 B, so row number contributes
// nothing to the bank index — in each 8-lane group of ds_read_b128, rows 0-7
// read the SAME 16B chunk column. Full 3-bit XOR spreads them bijectively:
//   LDS chunk_lds = chunk_logical ^ (row & 7)     (byte ^= (row&7)<<4, G4)
// Read side applies the XOR; staging keeps the LDS dest LINEAR (rule #21) and
// pre-permutes the GLOBAL source column instead:
//   thread t stages row t>>3, global f16 col = ((t&7) ^ ((t>>3)&7)) * 8
// (involution round-trip verified; 8-thread groups still cover one aligned
// 128B global block -> coalescing intact).
//
// Schedule per K-tile j (buf cur=j&1):
//   P1 { ds_read A-lo(8)+B-lo(4); BAR; prio1 16xMFMA Q1 prio0; BAR }
//   P2 { ds_read B-hi(4);         BAR; Q2; BAR }
//   P3 { ds_read A-hi(8);         BAR; Q3; BAR }
//   P4 { STAGE(j+2 -> buf[cur]);  BAR; Q4; s_waitcnt vmcnt(8); BAR }
// vmcnt(8) leaves the 8 just-issued loads in flight and guarantees tile j+1
// landed; vmcnt never reaches 0 until the tile-62 edge.
// ---------------------------------------------------------------------------
#define BM 256
#define BN 256
#define BK 64
#define NKT (IN_F / BK)          // 64
#define GRID_MT (M_ROWS / BM)    // 32
#define GRID_NT (OUT_F / BN)     // 43

__global__ __launch_bounds__(512, 2) void gemm_pipe(
    const _Float16* __restrict__ X, const _Float16* __restrict__ Wd,
    const float* __restrict__ scales, const float* __restrict__ bias,
    float* __restrict__ out)
{
  __shared__ char smem[131072];  // [2 bufs][A 32KB | B 32KB]

  // T1: XCD swizzle; nwg = 1376 % 8 == 0 -> simple form bijective
  const int cpx = (GRID_MT * GRID_NT) >> 3;        // 172
  const int wg = (blockIdx.x & 7) * cpx + (blockIdx.x >> 3);
  const int mt = wg & (GRID_MT - 1), nt = wg >> 5; // m-inner: same B-panel per XCD
  const int m0 = mt * BM, n0 = nt * BN;

  const int t = threadIdx.x;
  const int wave = t >> 6, lane = t & 63;
  const int wm = wave >> 2, wn = wave & 3;
  const int r16 = lane & 15;
  const int q = lane >> 4;                         // 16B piece within 64B k-half
  const int sw = r16 & 7;                          // row&7 for all frag rows
  const int c0 = ((q ^ sw) << 4);                  // swizzled chunk byte, k=0
  const int c1 = (((4 | q) ^ sw) << 4);            // swizzled chunk byte, k=1

  // Staging: thread t's 16B lands at linear LDS byte (issue*8192 + t*16)
  //   -> row = issue*64 + (t>>3), chunk_lds = t&7.
  // Content there must be logical chunk (t&7) ^ ((t>>3)&7).
  const int s_row0 = t >> 3;
  const int s_col  = (((t & 7) ^ ((t >> 3) & 7)) << 3);
  const _Float16* asrc = X  + (size_t)(m0 + s_row0) * IN_F + s_col;
  const _Float16* bsrc = Wd + (size_t)(n0 + s_row0) * IN_F + s_col;
  const int s_dst = wave * 1024;                   // wave-uniform; HW adds lane*16

  f32x4 acc[8][4] = {};
  f16x8 alo[4][2], ahi[4][2], blo[2][2], bhi[2][2];

#define STAGE(kt, b) do {                                                     \
    const _Float16* _a = asrc + (size_t)(kt) * BK;                            \
    const _Float16* _b = bsrc + (size_t)(kt) * BK;                            \
    _Pragma("unroll")                                                         \
    for (int i = 0; i < 4; ++i)                                               \
      __builtin_amdgcn_global_load_lds(                                       \
        (const __attribute__((address_space(1))) void*)(_a + (size_t)i * 64 * IN_F), \
        (__attribute__((address_space(3))) void*)(smem + (b) * 65536 + i * 8192 + s_dst), \
        16, 0, 0);                                                            \
    _Pragma("unroll")                                                         \
    for (int i = 0; i < 4; ++i)                                               \
      __builtin_amdgcn_global_load_lds(                                       \
        (const __attribute__((address_space(1))) void*)(_b + (size_t)i * 64 * IN_F), \
        (__attribute__((address_space(3))) void*)(smem + (b) * 65536 + 32768 + i * 8192 + s_dst), \
        16, 0, 0);                                                            \
  } while (0)

#define BAR   __builtin_amdgcn_s_barrier()
#define PRIO1 __builtin_amdgcn_s_setprio(1)
#define PRIO0 __builtin_amdgcn_s_setprio(0)
#define VMCNT8 asm volatile("s_waitcnt vmcnt(8)" ::: "memory")
#define VMCNT0 asm volatile("s_waitcnt vmcnt(0)" ::: "memory")

// Q-cluster: 16 MFMAs accumulating one C quadrant over K=64
#define QUAD(AM, BM_, AOFF, BOFF)                                             \
    _Pragma("unroll")                                                         \
    for (int k = 0; k < 2; ++k)                                               \
      _Pragma("unroll")                                                       \
      for (int m = 0; m < 4; ++m)                                             \
        _Pragma("unroll")                                                     \
        for (int n = 0; n < 2; ++n)                                           \
          acc[(AOFF) + m][(BOFF) + n] =                                       \
            __builtin_amdgcn_mfma_f32_16x16x32_f16(AM[m][k], BM_[n][k],       \
                                                   acc[(AOFF) + m][(BOFF) + n], 0, 0, 0)

// One K-tile: STG = stage tile (jj+2) into buf[cur]; W8/W0 = wait flavor
#define TILE(cur, jj, STG, W8, W0) do {                                       \
    const char* Ab = smem + (cur) * 65536;                                    \
    const char* Bb = Ab + 32768;                                              \
    /* P1: A-lo + B-lo reads, Q1 */                                           \
    _Pragma("unroll")                                                         \
    for (int m = 0; m < 4; ++m)                                               \
      _Pragma("unroll")                                                       \
      for (int k = 0; k < 2; ++k)                                             \
        alo[m][k] = *(const f16x8*)(Ab + ((wm * 128 + m * 16 + r16) << 7) + (k ? c1 : c0)); \
    _Pragma("unroll")                                                         \
    for (int n = 0; n < 2; ++n)                                               \
      _Pragma("unroll")                                                       \
      for (int k = 0; k < 2; ++k)                                             \
        blo[n][k] = *(const f16x8*)(Bb + ((wn * 64 + n * 16 + r16) << 7) + (k ? c1 : c0)); \
    BAR; PRIO1; QUAD(alo, blo, 0, 0); PRIO0; BAR;                             \
    /* P2: B-hi reads, Q2 */                                                  \
    _Pragma("unroll")                                                         \
    for (int n = 0; n < 2; ++n)                                               \
      _Pragma("unroll")                                                       \
      for (int k = 0; k < 2; ++k)                                             \
        bhi[n][k] = *(const f16x8*)(Bb + ((wn * 64 + (2 + n) * 16 + r16) << 7) + (k ? c1 : c0)); \
    BAR; PRIO1; QUAD(alo, bhi, 0, 2); PRIO0; BAR;                             \
    /* P3: A-hi reads, Q3 */                                                  \
    _Pragma("unroll")                                                         \
    for (int m = 0; m < 4; ++m)                                               \
      _Pragma("unroll")                                                       \
      for (int k = 0; k < 2; ++k)                                             \
        ahi[m][k] = *(const f16x8*)(Ab + ((wm * 128 + (4 + m) * 16 + r16) << 7) + (k ? c1 : c0)); \
    BAR; PRIO1; QUAD(ahi, bhi, 4, 2); PRIO0; BAR;                             \
    /* P4: stage j+2 into buf[cur] (all buf[cur] reads consumed by P3-end BAR) */ \
    if (STG) STAGE((jj) + 2, cur);                                            \
    BAR; PRIO1; QUAD(ahi, blo, 4, 0); PRIO0;                                  \
    if (W8) { VMCNT8; }                                                       \
    if (W0) { VMCNT0; }                                                       \
    if ((W8) || (W0)) BAR;  /* publish tile jj+1 */                           \
  } while (0)

  // Prologue: stage tiles 0 and 1; publish tile 0 with tile 1 still in flight
  STAGE(0, 0);
  STAGE(1, 1);
  VMCNT8;
  BAR;

  // Tiles 0..61: full pipeline (stage jj+2, counted wait vmcnt(8))
  #pragma unroll 1
  for (int jj = 0; jj < 62; jj += 2) {
    TILE(0, jj, 1, 1, 0);
    TILE(1, jj + 1, 1, 1, 0);
  }
  // Tile 62: no stage left; drain (edge) and publish tile 63
  TILE(0, 62, 0, 0, 1);
  // Tile 63: last; no stage, no wait
  TILE(1, 63, 0, 0, 0);

  // Epilogue: acc * scales[col] + bias[col], fp32.
  // C/D frag: col = lane&15, row = (lane>>4)*4 + reg (m89-verified).
  const int crow = (lane >> 4) << 2;
  #pragma unroll
  for (int nf = 0; nf < 4; ++nf) {
    const int col = n0 + wn * 64 + nf * 16 + r16;
    const float s = scales[col];
    const float bb = bias[col];
    #pragma unroll
    for (int mf = 0; mf < 8; ++mf) {
      const int rb = m0 + wm * 128 + mf * 16 + crow;
      #pragma unroll
      for (int r = 0; r < 4; ++r)
        out[(size_t)(rb + r) * OUT_F + col] = acc[mf][nf][r] * s + bb;
    }
  }
#undef TILE
#undef QUAD
#undef STAGE
}

// ---------------------------------------------------------------------------
// Fallback (only if ws too small): correct but slow fp32 path.
// ---------------------------------------------------------------------------
__global__ __launch_bounds__(256) void naive_kernel(
    const float* __restrict__ x, const int* __restrict__ codes,
    const float* __restrict__ cbs, const float* __restrict__ scales,
    const float* __restrict__ bias, float* __restrict__ out)
{
  __shared__ float xrow[IN_F];
  const int m = blockIdx.x;
  for (int i = threadIdx.x; i < IN_F; i += 256)
    xrow[i] = x[(size_t)m * IN_F + i];
  __syncthreads();
  for (int o = threadIdx.x; o < OUT_F; o += 256) {
    float acc = 0.f;
    const int2* crow = (const int2*)codes + (size_t)o * NIG;
    for (int g = 0; g < NIG; ++g) {
      const int2 c = crow[g];
      const float* e0 = cbs + (size_t)c.x * 8;
      const float* e1 = cbs + (size_t)CBSZ * 8 + (size_t)c.y * 8;
      const float* xr = xrow + g * 8;
      #pragma unroll
      for (int j = 0; j < 8; ++j) acc += (e0[j] + e1[j]) * xr[j];
    }
    out[(size_t)m * OUT_F + o] = acc * scales[o] + bias[o];
  }
}

// ---------------------------------------------------------------------------
extern "C" void kernel_launch(void* const* d_in, const int* in_sizes, int n_in,
                              void* d_out, int out_size, void* d_ws, size_t ws_size,
                              hipStream_t stream) {
  const float* x      = (const float*)d_in[0];
  const int*   codes  = (const int*)d_in[1];
  const float* cbs    = (const float*)d_in[2];
  const float* scales = (const float*)d_in[3];
  const float* bias   = (const float*)d_in[4];
  float* out = (float*)d_out;

  const size_t W_BYTES = (size_t)OUT_F * IN_F * sizeof(_Float16);  // 90.2 MB
  const size_t X_BYTES = (size_t)M_ROWS * IN_F * sizeof(_Float16); // 67.1 MB

  if (ws_size < W_BYTES + X_BYTES) {
    naive_kernel<<<M_ROWS, 256, 0, stream>>>(x, codes, cbs, scales, bias, out);
    return;
  }

  _Float16* W = (_Float16*)d_ws;
  _Float16* X = (_Float16*)((char*)d_ws + W_BYTES);

  dequant_w_kernel<<<(OUT_F * NIG) / 256, 256, 0, stream>>>(codes, cbs, W);
  convert_x_kernel<<<(M_ROWS * IN_F / 8) / 256, 256, 0, stream>>>(x, X);
  gemm_pipe<<<GRID_MT * GRID_NT, 512, 0, stream>>>(X, W, scales, bias, out);
}

// Round 6
// 799.357 us; speedup vs baseline: 1.1572x; 1.0502x over previous
//
#include <hip/hip_runtime.h>
#include <hip/hip_bf16.h>
#include <stdint.h>

// Problem constants (from reference)
#define IN_F 4096
#define OUT_F 11008
#define M_ROWS 8192              // 4 * 2048
#define NIG 512                  // IN_FEATURES / IN_GROUP(8)
#define CBSZ 256

typedef _Float16 f16x8 __attribute__((ext_vector_type(8)));
typedef float f32x4 __attribute__((ext_vector_type(4)));

// ---------------------------------------------------------------------------
// Kernel 1: dequantize W (UNSCALED: scales applied in GEMM epilogue in fp32).
// ---------------------------------------------------------------------------
__global__ __launch_bounds__(256) void dequant_w_kernel(
    const int* __restrict__ codes, const float* __restrict__ cbs,
    _Float16* __restrict__ W)
{
  const int idx = blockIdx.x * 256 + threadIdx.x;   // o*512 + g (exact grid)
  const int2 c = ((const int2*)codes)[idx];
  const float4* e0 = (const float4*)(cbs + (size_t)c.x * 8);
  const float4* e1 = (const float4*)(cbs + (size_t)CBSZ * 8 + (size_t)c.y * 8);
  const float4 a0 = e0[0], a1 = e0[1];
  const float4 b0 = e1[0], b1 = e1[1];
  f16x8 w;
  w[0] = (_Float16)(a0.x + b0.x);
  w[1] = (_Float16)(a0.y + b0.y);
  w[2] = (_Float16)(a0.z + b0.z);
  w[3] = (_Float16)(a0.w + b0.w);
  w[4] = (_Float16)(a1.x + b1.x);
  w[5] = (_Float16)(a1.y + b1.y);
  w[6] = (_Float16)(a1.z + b1.z);
  w[7] = (_Float16)(a1.w + b1.w);
  *(f16x8*)(W + (size_t)idx * 8) = w;
}

// ---------------------------------------------------------------------------
// Kernel 2: x fp32 -> f16, 8 elems/thread, vectorized.
// ---------------------------------------------------------------------------
__global__ __launch_bounds__(256) void convert_x_kernel(
    const float* __restrict__ x, _Float16* __restrict__ X)
{
  const size_t i = ((size_t)blockIdx.x * 256 + threadIdx.x) * 8;
  const float4 a = *(const float4*)(x + i);
  const float4 b = *(const float4*)(x + i + 4);
  f16x8 v;
  v[0] = (_Float16)a.x; v[1] = (_Float16)a.y;
  v[2] = (_Float16)a.z; v[3] = (_Float16)a.w;
  v[4] = (_Float16)b.x; v[5] = (_Float16)b.y;
  v[6] = (_Float16)b.z; v[7] = (_Float16)b.w;
  *(f16x8*)(X + i) = v;
}

// ---------------------------------------------------------------------------
// Kernel 3: 256x256x64 f16 GEMM — MODULO-SCHEDULED 8-phase pipeline.
// 512 threads = 8 waves (2M x 4N); per-wave output 128x64 (8x4 16x16 frags).
// LDS: 2 x (A [256][64] | B [256][64]) f16 = 128 KB. Bank swizzle (verified
// 0-conflict r4): chunk_lds = chunk ^ (row&7); read applies XOR, staging
// pre-permutes the GLOBAL source column, LDS dest stays linear.
//
// Per tile t (8 phases q1..q8, ONE barrier each; 8 MFMA each; quadrant x
// k-half Gray order). KEY: every MFMA consumes fragments ds_read >= 1 phase
// earlier, so LDS reads stream concurrently with MFMA (counted lgkm waits).
//   phase: MFMA group            ds_reads (for)        stages (2 calls)
//   q1:  Q1k0 al0*bl0[P]         al1(t)     [4]        A_h0(t+1)->bufN
//   q2:  Q1k1 al1*bl1            bh1(t)     [2]        A_h1(t+1)->bufN
//   q3:  Q2k1 al1*bh1            bh0(t)     [2]
//   q4:  Q2k0 al0*bh0            ah0(t)     [4]
//   q5:  Q3k0 ah0*bh0            ah1(t)     [4]
//   q6:  Q3k1 ah1*bh1            —          [0]        gate vmcnt(4)
//   q7:  Q4k1 ah1*bl1            bl0(t+1)   [2] gen^1  B_h0(t+2)->bufT, vmcnt(2)
//   q8:  Q4k0 ah0*bl0[P]         al0,bl1(t+1)[6]       B_h1(t+2)->bufT
// Gates: each wave waits its OWN stage-loads (vmcnt) then barriers -> all
// waves' loads landed. In-flight stays 4-8, never drains until tile 62.
// blo_k0 is double-generation (used q1 and q8 -> wraps tile boundary).
// ---------------------------------------------------------------------------
#define BM 256
#define BN 256
#define BK 64
#define NKT (IN_F / BK)          // 64
#define GRID_MT (M_ROWS / BM)    // 32
#define GRID_NT (OUT_F / BN)     // 43

__global__ __launch_bounds__(512, 2) void gemm_pipe(
    const _Float16* __restrict__ X, const _Float16* __restrict__ Wd,
    const float* __restrict__ scales, const float* __restrict__ bias,
    float* __restrict__ out)
{
  __shared__ char smem[131072];  // [2 bufs][A 32KB | B 32KB]

  // T1: XCD swizzle; nwg = 1376 % 8 == 0 -> simple form bijective
  const int cpx = (GRID_MT * GRID_NT) >> 3;        // 172
  const int wg = (blockIdx.x & 7) * cpx + (blockIdx.x >> 3);
  const int mt = wg & (GRID_MT - 1), nt = wg >> 5; // m-inner: same B-panel per XCD
  const int m0 = mt * BM, n0 = nt * BN;

  const int t_ = threadIdx.x;
  const int wave = t_ >> 6, lane = t_ & 63;
  const int wm = wave >> 2, wn = wave & 3;
  const int r16 = lane & 15;
  const int q = lane >> 4;                         // 16B piece within 64B k-half
  const int sw = r16 & 7;                          // row&7 (rows offset by mult of 16)
  const int c0 = ((q ^ sw) << 4);                  // swizzled chunk byte, k-half 0
  const int c1 = (((4 | q) ^ sw) << 4);            // swizzled chunk byte, k-half 1

  // Staging: thread t's 16B lands at linear LDS byte (call*8192 + t*16)
  //   -> row = call*64 + (t>>3), chunk_lds = t&7; logical chunk = (t&7)^((t>>3)&7)
  const int s_row0 = t_ >> 3;
  const int s_col  = (((t_ & 7) ^ ((t_ >> 3) & 7)) << 3);
  const _Float16* asrc = X  + (size_t)(m0 + s_row0) * IN_F + s_col;
  const _Float16* bsrc = Wd + (size_t)(n0 + s_row0) * IN_F + s_col;
  const int s_dst = wave * 1024;                   // wave-uniform; HW adds lane*16

  f32x4 acc[8][4] = {};
  // Fragment register classes (per modulo schedule). blo_k0 double-gen.
  f16x8 al0[4], al1[4], ah0[4], ah1[4];
  f16x8 bl0[2][2], bl1[2], bh0[2], bh1[2];

#define GLD(gsrc, ldst) __builtin_amdgcn_global_load_lds(                     \
    (const __attribute__((address_space(1))) void*)(gsrc),                    \
    (__attribute__((address_space(3))) void*)(ldst), 16, 0, 0)
#define STAGE_A(kt, bufc, i) GLD(asrc + (size_t)(kt) * BK + (size_t)(i) * 64 * IN_F, \
    smem + (bufc) * 65536 + (i) * 8192 + s_dst)
#define STAGE_B(kt, bufc, i) GLD(bsrc + (size_t)(kt) * BK + (size_t)(i) * 64 * IN_F, \
    smem + (bufc) * 65536 + 32768 + (i) * 8192 + s_dst)

#define RD_A(bufp, mm, cc) (*(const f16x8*)((bufp) + ((wm * 128 + (mm) * 16 + r16) << 7) + (cc)))
#define RD_B(bufp, nn, cc) (*(const f16x8*)((bufp) + 32768 + ((wn * 64 + (nn) * 16 + r16) << 7) + (cc)))

#define BAR   __builtin_amdgcn_s_barrier()
#define PRIO1 __builtin_amdgcn_s_setprio(1)
#define PRIO0 __builtin_amdgcn_s_setprio(0)
#define VM4 asm volatile("s_waitcnt vmcnt(4)" ::: "memory")
#define VM2 asm volatile("s_waitcnt vmcnt(2)" ::: "memory")
#define VM0 asm volatile("s_waitcnt vmcnt(0)" ::: "memory")

// 8-MFMA group: 4 m-frags x 2 n-frags into acc[MO..][NO..]
#define MG(AF, BF, MO, NO)                                                    \
    _Pragma("unroll")                                                         \
    for (int m = 0; m < 4; ++m)                                               \
      _Pragma("unroll")                                                       \
      for (int n = 0; n < 2; ++n)                                             \
        acc[(MO) + m][(NO) + n] = __builtin_amdgcn_mfma_f32_16x16x32_f16(     \
            AF[m], BF[n], acc[(MO) + m][(NO) + n], 0, 0, 0)

// One K-tile. P: parity literal. SA: stage A(t+1). SB: stage B(t+2).
// GB: q6 gate vmcnt(4). GA: q7 gate mode (2 -> vmcnt(2), 0 -> vmcnt(0), -1 none).
#define TILE(P, tt, SA, SB, GB, GA) do {                                      \
    char* bufT = smem + (P) * 65536;                                          \
    char* bufN = smem + (1 - (P)) * 65536;                                    \
    /* q1 */                                                                  \
    if (SA) { STAGE_A((tt) + 1, 1 - (P), 0); STAGE_A((tt) + 1, 1 - (P), 1); } \
    _Pragma("unroll")                                                         \
    for (int m = 0; m < 4; ++m) al1[m] = RD_A(bufT, m, c1);                   \
    PRIO1; MG(al0, bl0[P], 0, 0); PRIO0; BAR;                                 \
    /* q2 */                                                                  \
    if (SA) { STAGE_A((tt) + 1, 1 - (P), 2); STAGE_A((tt) + 1, 1 - (P), 3); } \
    _Pragma("unroll")                                                         \
    for (int n = 0; n < 2; ++n) bh1[n] = RD_B(bufT, 2 + n, c1);               \
    PRIO1; MG(al1, bl1, 0, 0); PRIO0; BAR;                                    \
    /* q3 */                                                                  \
    _Pragma("unroll")                                                         \
    for (int n = 0; n < 2; ++n) bh0[n] = RD_B(bufT, 2 + n, c0);               \
    PRIO1; MG(al1, bh1, 0, 2); PRIO0; BAR;                                    \
    /* q4 */                                                                  \
    _Pragma("unroll")                                                         \
    for (int m = 0; m < 4; ++m) ah0[m] = RD_A(bufT, 4 + m, c0);               \
    PRIO1; MG(al0, bh0, 0, 2); PRIO0; BAR;                                    \
    /* q5 */                                                                  \
    _Pragma("unroll")                                                         \
    for (int m = 0; m < 4; ++m) ah1[m] = RD_A(bufT, 4 + m, c1);               \
    PRIO1; MG(ah0, bh0, 4, 2); PRIO0; BAR;                                    \
    /* q6 */                                                                  \
    PRIO1; MG(ah1, bh1, 4, 2); PRIO0;                                         \
    if (GB) { VM4; }                                                          \
    BAR;                                                                      \
    /* q7 */                                                                  \
    if (SB) { STAGE_B((tt) + 2, P, 0); STAGE_B((tt) + 2, P, 1); }             \
    _Pragma("unroll")                                                         \
    for (int n = 0; n < 2; ++n) bl0[1 - (P)][n] = RD_B(bufN, n, c0);          \
    PRIO1; MG(ah1, bl1, 4, 0); PRIO0;                                         \
    if ((GA) == 2) { VM2; }                                                   \
    if ((GA) == 0) { VM0; }                                                   \
    BAR;                                                                      \
    /* q8 */                                                                  \
    if (SB) { STAGE_B((tt) + 2, P, 2); STAGE_B((tt) + 2, P, 3); }             \
    _Pragma("unroll")                                                         \
    for (int m = 0; m < 4; ++m) al0[m] = RD_A(bufN, m, c0);                   \
    _Pragma("unroll")                                                         \
    for (int n = 0; n < 2; ++n) bl1[n] = RD_B(bufN, n, c1);                   \
    PRIO1; MG(ah0, bl0[P], 4, 0); PRIO0; BAR;                                 \
  } while (0)

  // ---- Prologue: tile0 full (8 calls) + tile1 B (4 calls); enter steady state
  {
    _Pragma("unroll")
    for (int i = 0; i < 4; ++i) { STAGE_A(0, 0, i); }
    _Pragma("unroll")
    for (int i = 0; i < 4; ++i) { STAGE_B(0, 0, i); }
    _Pragma("unroll")
    for (int i = 0; i < 4; ++i) { STAGE_B(1, 1, i); }
    VM4;                                   // tile0's 8 landed; tile1-B 4 in flight
    BAR;
    // Preload registers the steady loop expects (normally read at q7/q8(t-1)):
    char* buf0p = smem;
    _Pragma("unroll")
    for (int n = 0; n < 2; ++n) bl0[0][n] = RD_B(buf0p, n, c0);
    _Pragma("unroll")
    for (int n = 0; n < 2; ++n) bl1[n] = RD_B(buf0p, n, c1);
    _Pragma("unroll")
    for (int m = 0; m < 4; ++m) al0[m] = RD_A(buf0p, m, c0);
  }

  // ---- Main loop: tiles 0..61 (full pipeline)
  #pragma unroll 1
  for (int t = 0; t < 62; t += 2) {
    TILE(0, t,     1, 1, 1, 2);
    TILE(1, t + 1, 1, 1, 1, 2);
  }
  // ---- Tail: tile 62 (stage A(63) only; drain gate), tile 63 (no stages/gates;
  // its q7/q8 prefetch-reads fetch stale LDS, dead values — harmless)
  TILE(0, 62, 1, 0, 1, 0);
  TILE(1, 63, 0, 0, 0, -1);

  // Epilogue: acc * scales[col] + bias[col], fp32.
  // C/D frag: col = lane&15, row = (lane>>4)*4 + reg (m89-verified).
  const int crow = (lane >> 4) << 2;
  #pragma unroll
  for (int nf = 0; nf < 4; ++nf) {
    const int col = n0 + wn * 64 + nf * 16 + r16;
    const float s = scales[col];
    const float bb = bias[col];
    #pragma unroll
    for (int mf = 0; mf < 8; ++mf) {
      const int rb = m0 + wm * 128 + mf * 16 + crow;
      #pragma unroll
      for (int r = 0; r < 4; ++r)
        out[(size_t)(rb + r) * OUT_F + col] = acc[mf][nf][r] * s + bb;
    }
  }
#undef TILE
#undef MG
#undef RD_A
#undef RD_B
#undef STAGE_A
#undef STAGE_B
#undef GLD
}

// ---------------------------------------------------------------------------
// Fallback (only if ws too small): correct but slow fp32 path.
// ---------------------------------------------------------------------------
__global__ __launch_bounds__(256) void naive_kernel(
    const float* __restrict__ x, const int* __restrict__ codes,
    const float* __restrict__ cbs, const float* __restrict__ scales,
    const float* __restrict__ bias, float* __restrict__ out)
{
  __shared__ float xrow[IN_F];
  const int m = blockIdx.x;
  for (int i = threadIdx.x; i < IN_F; i += 256)
    xrow[i] = x[(size_t)m * IN_F + i];
  __syncthreads();
  for (int o = threadIdx.x; o < OUT_F; o += 256) {
    float acc = 0.f;
    const int2* crow = (const int2*)codes + (size_t)o * NIG;
    for (int g = 0; g < NIG; ++g) {
      const int2 c = crow[g];
      const float* e0 = cbs + (size_t)c.x * 8;
      const float* e1 = cbs + (size_t)CBSZ * 8 + (size_t)c.y * 8;
      const float* xr = xrow + g * 8;
      #pragma unroll
      for (int j = 0; j < 8; ++j) acc += (e0[j] + e1[j]) * xr[j];
    }
    out[(size_t)m * OUT_F + o] = acc * scales[o] + bias[o];
  }
}

// ---------------------------------------------------------------------------
extern "C" void kernel_launch(void* const* d_in, const int* in_sizes, int n_in,
                              void* d_out, int out_size, void* d_ws, size_t ws_size,
                              hipStream_t stream) {
  const float* x      = (const float*)d_in[0];
  const int*   codes  = (const int*)d_in[1];
  const float* cbs    = (const float*)d_in[2];
  const float* scales = (const float*)d_in[3];
  const float* bias   = (const float*)d_in[4];
  float* out = (float*)d_out;

  const size_t W_BYTES = (size_t)OUT_F * IN_F * sizeof(_Float16);  // 90.2 MB
  const size_t X_BYTES = (size_t)M_ROWS * IN_F * sizeof(_Float16); // 67.1 MB

  if (ws_size < W_BYTES + X_BYTES) {
    naive_kernel<<<M_ROWS, 256, 0, stream>>>(x, codes, cbs, scales, bias, out);
    return;
  }

  _Float16* W = (_Float16*)d_ws;
  _Float16* X = (_Float16*)((char*)d_ws + W_BYTES);

  dequant_w_kernel<<<(OUT_F * NIG) / 256, 256, 0, stream>>>(codes, cbs, W);
  convert_x_kernel<<<(M_ROWS * IN_F / 8) / 256, 256, 0, stream>>>(x, X);
  gemm_pipe<<<GRID_MT * GRID_NT, 512, 0, stream>>>(X, W, scales, bias, out);
}